// Round 3
// baseline (641.776 us; speedup 1.0000x reference)
//
#include <hip/hip_runtime.h>

typedef _Float16 f16x8 __attribute__((ext_vector_type(8)));
typedef float f32x4 __attribute__((ext_vector_type(4)));

#define MFMA16(a, b, c) __builtin_amdgcn_mfma_f32_16x16x32_f16(a, b, c, 0, 0, 0)

// ---- ws byte offsets (all 16B aligned) ----
#define OFF_W1   0u        // eW1  512x512 f16 packed (524288 B)
#define OFF_W2   524288u   // eW2  512x128 (131072 B)
#define OFF_W3   655360u   // eW3  128x64  (16384 B)
#define OFF_W4   671744u   // dW1' 64x128  (16384 B)  = (H64 dW1) * w1c/8
#define OFF_W5   688128u   // dW2  128x32  (8192 B)
#define OFF_W6   696320u   // pW'  32x32   (2048 B)   = (H32 pW) * w2c/sqrt(32)
#define OFF_DB1  698368u   // db1' 128 f32 (512 B)    = db1 + w1b*colsum(dW1)
#define OFF_PB   698880u   // pb'  32 f32  (128 B)    = pb  + w2b*colsum(pW)

// Pack W[K][N] (row-major f32) into MFMA-B fragment order:
// dst[((kk*NF + nf)*64 + lane)*8 + j] = W[kk*32 + (lane>>4)*8 + j][nf*16 + (lane&15)]
__device__ inline void packw(int local, int N, const float* __restrict__ W,
                             _Float16* __restrict__ dst) {
  int j = local & 7;
  int lane = (local >> 3) & 63;
  int fi = local >> 9;
  int NF = N >> 4;
  int nf = fi % NF;
  int kk = fi / NF;
  int k = kk * 32 + ((lane >> 4) << 3) + j;
  int n = (nf << 4) + (lane & 15);
  dst[local] = (_Float16)W[k * N + n];
}

// Same, but source = scale * (H_K @ W),  H[k][m] = (-1)^popc(k&m)
__device__ inline void packh(int local, int N, int K, const float* __restrict__ W,
                             _Float16* __restrict__ dst, float scale) {
  int j = local & 7;
  int lane = (local >> 3) & 63;
  int fi = local >> 9;
  int NF = N >> 4;
  int nf = fi % NF;
  int kk = fi / NF;
  int k = kk * 32 + ((lane >> 4) << 3) + j;
  int n = (nf << 4) + (lane & 15);
  float s = 0.f;
  for (int m = 0; m < K; ++m) {
    float v = W[m * N + n];
    s += (__popc(k & m) & 1) ? -v : v;
  }
  dst[local] = (_Float16)(s * scale);
}

extern "C" __global__ __launch_bounds__(256) void prep_kernel(
    const float* __restrict__ eW1, const float* __restrict__ eW2,
    const float* __restrict__ eW3, const float* __restrict__ dW1,
    const float* __restrict__ dW2, const float* __restrict__ pW,
    const float* __restrict__ w1c, const float* __restrict__ w1b,
    const float* __restrict__ w2c, const float* __restrict__ w2b,
    const float* __restrict__ db1, const float* __restrict__ pb,
    char* __restrict__ ws) {
  int idx = blockIdx.x * 256 + threadIdx.x;
  if (idx < 262144) {
    packw(idx, 512, eW1, (_Float16*)(ws + OFF_W1));
  } else if (idx < 327680) {
    packw(idx - 262144, 128, eW2, (_Float16*)(ws + OFF_W2));
  } else if (idx < 335872) {
    packw(idx - 327680, 64, eW3, (_Float16*)(ws + OFF_W3));
  } else if (idx < 344064) {
    packh(idx - 335872, 128, 64, dW1, (_Float16*)(ws + OFF_W4), w1c[0] * 0.125f);
  } else if (idx < 348160) {
    packw(idx - 344064, 32, dW2, (_Float16*)(ws + OFF_W5));
  } else if (idx < 349184) {
    packh(idx - 348160, 32, 32, pW, (_Float16*)(ws + OFF_W6),
          w2c[0] * 0.17677669529663687f);  // 1/sqrt(32)
  } else if (idx < 349312) {
    int n = idx - 349184;
    float s = 0.f;
    for (int m = 0; m < 64; ++m) s += dW1[m * 128 + n];
    ((float*)(ws + OFF_DB1))[n] = db1[n] + w1b[0] * s;
  } else if (idx < 349344) {
    int n = idx - 349312;
    float s = 0.f;
    for (int m = 0; m < 32; ++m) s += pW[m * 32 + n];
    ((float*)(ws + OFF_PB))[n] = pb[n] + w2b[0] * s;
  }
}

// ---- LDS layout: XOR-swizzled row-major; nu = 16B units per row (LD/8) ----
// A-fragment reads (16 lanes, same unit, rows 0..15) land <=2 lanes/bank -> free.
__device__ inline int hidx(int row, int col, int nu) {
  int u = (col >> 3) ^ ((row & 7) & (nu - 1));
  return row * (nu << 3) + (u << 3) + (col & 7);
}

__device__ inline f16x8 afrag(const _Float16* __restrict__ h, int row, int col, int nu) {
  return *(const f16x8*)(h + hidx(row, col, nu));  // col % 8 == 0 -> 16B aligned
}

// Generic layer: out[32][16*NF] = act(in[32][KSTEPS*32] @ W + bias); wave w owns nf=w.
template <int KSTEPS, int NUIN, int NUOUT, bool RELU>
__device__ inline void mlayer(const _Float16* __restrict__ hin, _Float16* __restrict__ hout,
                              const f16x8* __restrict__ Wp, const float* __restrict__ bias,
                              int NF, int w, int lane, int g, int rr) {
  if (w < NF) {
    const int nf = w;
    f32x4 acc0 = {0.f, 0.f, 0.f, 0.f};
    f32x4 acc1 = {0.f, 0.f, 0.f, 0.f};
#pragma unroll
    for (int kk = 0; kk < KSTEPS; ++kk) {
      f16x8 a0 = afrag(hin, rr, kk * 32 + g * 8, NUIN);
      f16x8 a1 = afrag(hin, 16 + rr, kk * 32 + g * 8, NUIN);
      f16x8 b = Wp[(kk * NF + nf) * 64 + lane];
      acc0 = MFMA16(a0, b, acc0);
      acc1 = MFMA16(a1, b, acc1);
    }
    const int n = nf * 16 + rr;
    const float bv = bias[n];
#pragma unroll
    for (int i = 0; i < 4; ++i) {
      float v0 = acc0[i] + bv;
      float v1 = acc1[i] + bv;
      if (RELU) {
        v0 = fmaxf(v0, 0.f);
        v1 = fmaxf(v1, 0.f);
      }
      hout[hidx(g * 4 + i, n, NUOUT)] = (_Float16)v0;
      hout[hidx(16 + g * 4 + i, n, NUOUT)] = (_Float16)v1;
    }
  }
}

// Textually-inlined downsample: xv[16] must stay in registers (all indices
// compile-time after unroll; NO function-call/pointer-decay -> SROA-safe).
#define DOWNSAMPLE(XV)                                            \
  do {                                                            \
    _Pragma("unroll") for (int i_ = 0; i_ < 16; ++i_) {           \
      float4 v_ = (XV)[i_];                                       \
      int f_ = tid + i_ * 512; /* f = r*256 + t */                \
      int r_ = f_ >> 8;                                           \
      int t_ = f_ & 255;                                          \
      float R_ = v_.x * d10 + v_.y * d11 + v_.z * d12 + v_.w * d13; \
      float Z_ = v_.x * d20 + v_.y * d21 + v_.z * d22 + v_.w * d23; \
      hA[hidx(r_, t_, 64)] = (_Float16)R_;                        \
      hA[hidx(r_, 256 + t_, 64)] = (_Float16)Z_;                  \
    }                                                             \
  } while (0)

// ---- persistent fused kernel: 512 WGs x 4 blocks of 32 rows ----
// LDS aliasing (all hazards separated by >=1 barrier):
//   hA: h0 (32x512 nu64) -> h2 (32x128 nu16) -> h4 (32x128 nu16) -> next h0
//   hB: h1 (32x512 nu64) -> h3 (32x64 nu8)  -> h5 (32x32 nu4)
#define NB 4
#define GRID 512

extern "C" __global__ __launch_bounds__(512, 4) void fused_kernel(
    const float* __restrict__ x, const float* __restrict__ dw1,
    const float* __restrict__ dw2, const float* __restrict__ eb1,
    const float* __restrict__ eb2, const float* __restrict__ eb3,
    const float* __restrict__ db2, const char* __restrict__ ws,
    float* __restrict__ out) {
  __shared__ __align__(16) _Float16 hA[32 * 512];
  __shared__ __align__(16) _Float16 hB[32 * 512];

  const int tid = threadIdx.x;
  const int wg = blockIdx.x;
  const int lane = tid & 63;
  const int w = tid >> 6;
  const int g = lane >> 4;
  const int rr = lane & 15;

  const float d10 = dw1[0], d11 = dw1[1], d12 = dw1[2], d13 = dw1[3];
  const float d20 = dw2[0], d21 = dw2[1], d22 = dw2[2], d23 = dw2[3];

  const f16x8* __restrict__ W1 = (const f16x8*)(ws + OFF_W1);
  const f16x8* __restrict__ W2 = (const f16x8*)(ws + OFF_W2);
  const f16x8* __restrict__ W3 = (const f16x8*)(ws + OFF_W3);
  const f16x8* __restrict__ W4 = (const f16x8*)(ws + OFF_W4);
  const f16x8* __restrict__ W5 = (const f16x8*)(ws + OFF_W5);
  const f16x8* __restrict__ W6 = (const f16x8*)(ws + OFF_W6);
  const float* __restrict__ db1p = (const float*)(ws + OFF_DB1);
  const float* __restrict__ pbp = (const float*)(ws + OFF_PB);

  float4 xv[16];

  // ---- prologue: stage + downsample block wg ----
  {
    const float4* __restrict__ xp = (const float4*)x + (size_t)wg * 8192;
#pragma unroll
    for (int i = 0; i < 16; ++i) xv[i] = xp[tid + i * 512];
    DOWNSAMPLE(xv);
  }
  __syncthreads();

  for (int it = 0; it < NB; ++it) {
    const bool pf = (it < NB - 1);
    const float4* __restrict__ xn = (const float4*)x + (size_t)(wg + GRID * (it + 1)) * 8192;
    if (pf) {
#pragma unroll
      for (int i = 0; i < 8; ++i) xv[i] = xn[tid + i * 512];  // in flight across L1..L2
    }

    // ---- L1: h1 = relu(h0 @ eW1 + eb1), hA -> hB; 8 waves x 4 nf ----
    {
      f32x4 acc[2][4];
#pragma unroll
      for (int m = 0; m < 2; ++m)
#pragma unroll
        for (int n = 0; n < 4; ++n) acc[m][n] = (f32x4){0.f, 0.f, 0.f, 0.f};
      const int nf0 = w * 4;
#pragma unroll
      for (int kk = 0; kk < 16; ++kk) {
        f16x8 a0 = afrag(hA, rr, kk * 32 + g * 8, 64);
        f16x8 a1 = afrag(hA, 16 + rr, kk * 32 + g * 8, 64);
#pragma unroll
        for (int nf = 0; nf < 4; ++nf) {
          f16x8 b = W1[(kk * 32 + nf0 + nf) * 64 + lane];
          acc[0][nf] = MFMA16(a0, b, acc[0][nf]);
          acc[1][nf] = MFMA16(a1, b, acc[1][nf]);
        }
      }
#pragma unroll
      for (int nf = 0; nf < 4; ++nf) {
        const int n = (nf0 + nf) * 16 + rr;
        const float bv = eb1[n];
#pragma unroll
        for (int i = 0; i < 4; ++i) {
          float v0 = fmaxf(acc[0][nf][i] + bv, 0.f);
          float v1 = fmaxf(acc[1][nf][i] + bv, 0.f);
          hB[hidx(g * 4 + i, n, 64)] = (_Float16)v0;
          hB[hidx(16 + g * 4 + i, n, 64)] = (_Float16)v1;
        }
      }
    }
    __syncthreads();

    // L2: h2 = relu(h1 @ eW2 + eb2), hB(nu64) -> hA(nu16)
    mlayer<16, 64, 16, true>(hB, hA, W2, eb2, 8, w, lane, g, rr);
    __syncthreads();

    if (pf) {
#pragma unroll
      for (int i = 8; i < 16; ++i) xv[i] = xn[tid + i * 512];  // in flight L3..L5
    }

    // L3: h3 = h2 @ eW3 + eb3 (FWHT folded forward), hA(nu16) -> hB(nu8)
    mlayer<4, 16, 8, false>(hA, hB, W3, eb3, 4, w, lane, g, rr);
    __syncthreads();
    // L4: h4 = relu(h3 @ dW1' + db1'), hB(nu8) -> hA(nu16)
    mlayer<2, 8, 16, true>(hB, hA, W4, db1p, 8, w, lane, g, rr);
    __syncthreads();
    // L5: h5 = h4 @ dW2 + db2, hA(nu16) -> hB(nu4)
    mlayer<4, 16, 4, false>(hA, hB, W5, db2, 2, w, lane, g, rr);
    __syncthreads();

    // ---- L6: out = h5 @ pW' + pb' (waves 0-1); all waves then downsample next h0 ----
    if (w < 2) {
      f32x4 acc0 = {0.f, 0.f, 0.f, 0.f};
      f32x4 acc1 = {0.f, 0.f, 0.f, 0.f};
      f16x8 a0 = afrag(hB, rr, g * 8, 4);
      f16x8 a1 = afrag(hB, 16 + rr, g * 8, 4);
      f16x8 b = W6[w * 64 + lane];
      acc0 = MFMA16(a0, b, acc0);
      acc1 = MFMA16(a1, b, acc1);
      const int n = w * 16 + rr;
      const float bv = pbp[n];
      const size_t rbase = (size_t)(wg + GRID * it) * 32;
#pragma unroll
      for (int i = 0; i < 4; ++i) {
        out[(rbase + g * 4 + i) * 32 + n] = acc0[i] + bv;
        out[(rbase + 16 + g * 4 + i) * 32 + n] = acc1[i] + bv;
      }
    }
    if (pf) DOWNSAMPLE(xv);
    __syncthreads();
  }
}

extern "C" void kernel_launch(void* const* d_in, const int* in_sizes, int n_in,
                              void* d_out, int out_size, void* d_ws, size_t ws_size,
                              hipStream_t stream) {
  const float* x = (const float*)d_in[0];
  const float* dw1 = (const float*)d_in[1];
  const float* dw2 = (const float*)d_in[2];
  const float* eW1 = (const float*)d_in[3];
  const float* eb1 = (const float*)d_in[4];
  const float* eW2 = (const float*)d_in[5];
  const float* eb2 = (const float*)d_in[6];
  const float* eW3 = (const float*)d_in[7];
  const float* eb3 = (const float*)d_in[8];
  const float* w1c = (const float*)d_in[9];
  const float* w1b = (const float*)d_in[10];
  const float* dW1 = (const float*)d_in[11];
  const float* db1 = (const float*)d_in[12];
  const float* dW2 = (const float*)d_in[13];
  const float* db2 = (const float*)d_in[14];
  const float* w2c = (const float*)d_in[15];
  const float* w2b = (const float*)d_in[16];
  const float* pW = (const float*)d_in[17];
  const float* pb = (const float*)d_in[18];
  char* ws = (char*)d_ws;
  float* out = (float*)d_out;

  prep_kernel<<<dim3(1365), dim3(256), 0, stream>>>(eW1, eW2, eW3, dW1, dW2, pW, w1c, w1b,
                                                    w2c, w2b, db1, pb, ws);
  fused_kernel<<<dim3(GRID), dim3(512), 0, stream>>>(x, dw1, dw2, eb1, eb2, eb3, db2, ws,
                                                     out);
}

// Round 4
// 636.326 us; speedup vs baseline: 1.0086x; 1.0086x over previous
//
#include <hip/hip_runtime.h>

typedef _Float16 f16x8 __attribute__((ext_vector_type(8)));
typedef float f32x4 __attribute__((ext_vector_type(4)));

#define MFMA16(a, b, c) __builtin_amdgcn_mfma_f32_16x16x32_f16(a, b, c, 0, 0, 0)

// ---- ws byte offsets (all 16B aligned) ----
#define OFF_W1   0u        // eW1  512x512 f16 packed (524288 B)
#define OFF_W2   524288u   // eW2  512x128 (131072 B)
#define OFF_W3   655360u   // eW3  128x64  (16384 B)
#define OFF_W4   671744u   // dW1' 64x128  (16384 B)  = (H64 dW1) * w1c/8
#define OFF_W5   688128u   // dW2  128x32  (8192 B)
#define OFF_W6   696320u   // pW'  32x32   (2048 B)   = (H32 pW) * w2c/sqrt(32)
#define OFF_DB1  698368u   // db1' 128 f32 (512 B)    = db1 + w1b*colsum(dW1)
#define OFF_PB   698880u   // pb'  32 f32  (128 B)    = pb  + w2b*colsum(pW)

__device__ inline void packw(int local, int N, const float* __restrict__ W,
                             _Float16* __restrict__ dst) {
  int j = local & 7;
  int lane = (local >> 3) & 63;
  int fi = local >> 9;
  int NF = N >> 4;
  int nf = fi % NF;
  int kk = fi / NF;
  int k = kk * 32 + ((lane >> 4) << 3) + j;
  int n = (nf << 4) + (lane & 15);
  dst[local] = (_Float16)W[k * N + n];
}

__device__ inline void packh(int local, int N, int K, const float* __restrict__ W,
                             _Float16* __restrict__ dst, float scale) {
  int j = local & 7;
  int lane = (local >> 3) & 63;
  int fi = local >> 9;
  int NF = N >> 4;
  int nf = fi % NF;
  int kk = fi / NF;
  int k = kk * 32 + ((lane >> 4) << 3) + j;
  int n = (nf << 4) + (lane & 15);
  float s = 0.f;
  for (int m = 0; m < K; ++m) {
    float v = W[m * N + n];
    s += (__popc(k & m) & 1) ? -v : v;
  }
  dst[local] = (_Float16)(s * scale);
}

extern "C" __global__ __launch_bounds__(256) void prep_kernel(
    const float* __restrict__ eW1, const float* __restrict__ eW2,
    const float* __restrict__ eW3, const float* __restrict__ dW1,
    const float* __restrict__ dW2, const float* __restrict__ pW,
    const float* __restrict__ w1c, const float* __restrict__ w1b,
    const float* __restrict__ w2c, const float* __restrict__ w2b,
    const float* __restrict__ db1, const float* __restrict__ pb,
    char* __restrict__ ws) {
  int idx = blockIdx.x * 256 + threadIdx.x;
  if (idx < 262144) {
    packw(idx, 512, eW1, (_Float16*)(ws + OFF_W1));
  } else if (idx < 327680) {
    packw(idx - 262144, 128, eW2, (_Float16*)(ws + OFF_W2));
  } else if (idx < 335872) {
    packw(idx - 327680, 64, eW3, (_Float16*)(ws + OFF_W3));
  } else if (idx < 344064) {
    packh(idx - 335872, 128, 64, dW1, (_Float16*)(ws + OFF_W4), w1c[0] * 0.125f);
  } else if (idx < 348160) {
    packw(idx - 344064, 32, dW2, (_Float16*)(ws + OFF_W5));
  } else if (idx < 349184) {
    packh(idx - 348160, 32, 32, pW, (_Float16*)(ws + OFF_W6),
          w2c[0] * 0.17677669529663687f);  // 1/sqrt(32)
  } else if (idx < 349312) {
    int n = idx - 349184;
    float s = 0.f;
    for (int m = 0; m < 64; ++m) s += dW1[m * 128 + n];
    ((float*)(ws + OFF_DB1))[n] = db1[n] + w1b[0] * s;
  } else if (idx < 349344) {
    int n = idx - 349312;
    float s = 0.f;
    for (int m = 0; m < 32; ++m) s += pW[m * 32 + n];
    ((float*)(ws + OFF_PB))[n] = pb[n] + w2b[0] * s;
  }
}

// ---- LDS layout: XOR-swizzled row-major; nu = 16B units per row ----
__device__ inline int hidx(int row, int col, int nu) {
  int u = (col >> 3) ^ ((row & 7) & (nu - 1));
  return row * (nu << 3) + (u << 3) + (col & 7);
}

__device__ inline f16x8 afrag(const _Float16* h, int row, int col, int nu) {
  return *(const f16x8*)(h + hidx(row, col, nu));  // col % 8 == 0 -> 16B aligned
}

// Generic layer: out[32][16*NF] = act(in[32][KSTEPS*32] @ W + bias); wave w owns nf=w.
template <int KSTEPS, int NUIN, int NUOUT, bool RELU>
__device__ inline void mlayer(const _Float16* hin, _Float16* hout,
                              const f16x8* __restrict__ Wp, const float* __restrict__ bias,
                              int NF, int w, int lane, int g, int rr) {
  if (w < NF) {
    const int nf = w;
    f32x4 acc0 = {0.f, 0.f, 0.f, 0.f};
    f32x4 acc1 = {0.f, 0.f, 0.f, 0.f};
#pragma unroll
    for (int kk = 0; kk < KSTEPS; ++kk) {
      f16x8 a0 = afrag(hin, rr, kk * 32 + g * 8, NUIN);
      f16x8 a1 = afrag(hin, 16 + rr, kk * 32 + g * 8, NUIN);
      f16x8 b = Wp[(kk * NF + nf) * 64 + lane];
      acc0 = MFMA16(a0, b, acc0);
      acc1 = MFMA16(a1, b, acc1);
    }
    const int n = nf * 16 + rr;
    const float bv = bias[n];
#pragma unroll
    for (int i = 0; i < 4; ++i) {
      float v0 = acc0[i] + bv;
      float v1 = acc1[i] + bv;
      if (RELU) {
        v0 = fmaxf(v0, 0.f);
        v1 = fmaxf(v1, 0.f);
      }
      hout[hidx(g * 4 + i, n, NUOUT)] = (_Float16)v0;
      hout[hidx(16 + g * 4 + i, n, NUOUT)] = (_Float16)v1;
    }
  }
}

// Convert one named float4 (index I in 0..15) -> h0 rows f>>8, cols f&255 / +256
#define CONV1(V, I, H)                                                  \
  do {                                                                  \
    int f_ = tid + (I) * 512;                                           \
    int r_ = f_ >> 8;                                                   \
    int t_ = f_ & 255;                                                  \
    float R_ = (V).x * d10 + (V).y * d11 + (V).z * d12 + (V).w * d13;   \
    float Z_ = (V).x * d20 + (V).y * d21 + (V).z * d22 + (V).w * d23;   \
    (H)[hidx(r_, t_, 64)] = (_Float16)R_;                               \
    (H)[hidx(r_, 256 + t_, 64)] = (_Float16)Z_;                         \
  } while (0)

#define LOADA(P)            \
  do {                      \
    x0 = (P)[tid + 0 * 512]; \
    x1 = (P)[tid + 1 * 512]; \
    x2 = (P)[tid + 2 * 512]; \
    x3 = (P)[tid + 3 * 512]; \
    x4 = (P)[tid + 4 * 512]; \
    x5 = (P)[tid + 5 * 512]; \
    x6 = (P)[tid + 6 * 512]; \
    x7 = (P)[tid + 7 * 512]; \
  } while (0)

#define LOADB(P)             \
  do {                       \
    y0 = (P)[tid + 8 * 512];  \
    y1 = (P)[tid + 9 * 512];  \
    y2 = (P)[tid + 10 * 512]; \
    y3 = (P)[tid + 11 * 512]; \
    y4 = (P)[tid + 12 * 512]; \
    y5 = (P)[tid + 13 * 512]; \
    y6 = (P)[tid + 14 * 512]; \
    y7 = (P)[tid + 15 * 512]; \
  } while (0)

#define CONVA(H)        \
  do {                  \
    CONV1(x0, 0, H);    \
    CONV1(x1, 1, H);    \
    CONV1(x2, 2, H);    \
    CONV1(x3, 3, H);    \
    CONV1(x4, 4, H);    \
    CONV1(x5, 5, H);    \
    CONV1(x6, 6, H);    \
    CONV1(x7, 7, H);    \
  } while (0)

#define CONVB(H)        \
  do {                  \
    CONV1(y0, 8, H);    \
    CONV1(y1, 9, H);    \
    CONV1(y2, 10, H);   \
    CONV1(y3, 11, H);   \
    CONV1(y4, 12, H);   \
    CONV1(y5, 13, H);   \
    CONV1(y6, 14, H);   \
    CONV1(y7, 15, H);   \
  } while (0)

// ---- persistent fused kernel: 512 WGs x 4 blocks of 32 rows ----
// LDS (80 KB total -> 2 WG/CU):
//   hA/hB (32K each): h0 / h1, roles swap by iteration parity.
//     h1's buffer is fully dead after L2 -> next-block h0 converted into it.
//   side (16K): slotA = h2/h4 (nu16, 8K), slotB = h3 (nu8, 4K), slotC = h5 (nu4, 2K)
#define NB 4
#define GRID 512

extern "C" __global__ __launch_bounds__(512, 4) void fused_kernel(
    const float* __restrict__ x, const float* __restrict__ dw1,
    const float* __restrict__ dw2, const float* __restrict__ eb1,
    const float* __restrict__ eb2, const float* __restrict__ eb3,
    const float* __restrict__ db2, const char* __restrict__ ws,
    float* __restrict__ out) {
  __shared__ __align__(16) _Float16 hA[32 * 512];
  __shared__ __align__(16) _Float16 hB[32 * 512];
  __shared__ __align__(16) _Float16 side[8192];
  _Float16* const slotA = side;         // 32x128 nu16
  _Float16* const slotB = side + 4096;  // 32x64  nu8
  _Float16* const slotC = side + 6144;  // 32x32  nu4

  const int tid = threadIdx.x;
  const int wg = blockIdx.x;
  const int lane = tid & 63;
  const int w = tid >> 6;
  const int g = lane >> 4;
  const int rr = lane & 15;

  const float d10 = dw1[0], d11 = dw1[1], d12 = dw1[2], d13 = dw1[3];
  const float d20 = dw2[0], d21 = dw2[1], d22 = dw2[2], d23 = dw2[3];

  const f16x8* __restrict__ W1 = (const f16x8*)(ws + OFF_W1);
  const f16x8* __restrict__ W2 = (const f16x8*)(ws + OFF_W2);
  const f16x8* __restrict__ W3 = (const f16x8*)(ws + OFF_W3);
  const f16x8* __restrict__ W4 = (const f16x8*)(ws + OFF_W4);
  const f16x8* __restrict__ W5 = (const f16x8*)(ws + OFF_W5);
  const f16x8* __restrict__ W6 = (const f16x8*)(ws + OFF_W6);
  const float* __restrict__ db1p = (const float*)(ws + OFF_DB1);
  const float* __restrict__ pbp = (const float*)(ws + OFF_PB);

  float4 x0, x1, x2, x3, x4, x5, x6, x7;
  float4 y0, y1, y2, y3, y4, y5, y6, y7;

  // ---- prologue: stage + convert block wg into hA ----
  {
    const float4* __restrict__ xp = (const float4*)x + (size_t)wg * 8192;
    LOADA(xp);
    LOADB(xp);
    CONVA(hA);
    CONVB(hA);
  }
  __syncthreads();

  for (int it = 0; it < NB; ++it) {
    const bool pf = (it < NB - 1);
    _Float16* const h0b = (it & 1) ? hB : hA;
    _Float16* const h1b = (it & 1) ? hA : hB;
    const float4* __restrict__ xn =
        (const float4*)x + (size_t)(wg + GRID * (it + 1)) * 8192;

    if (pf) LOADA(xn);  // in flight across L1+L2

    // ---- L1: h1 = relu(h0 @ eW1 + eb1), h0b -> h1b; 8 waves x 4 nf ----
    {
      f32x4 acc[2][4];
#pragma unroll
      for (int m = 0; m < 2; ++m)
#pragma unroll
        for (int n = 0; n < 4; ++n) acc[m][n] = (f32x4){0.f, 0.f, 0.f, 0.f};
      const int nf0 = w * 4;
#pragma unroll
      for (int kk = 0; kk < 16; ++kk) {
        f16x8 a0 = afrag(h0b, rr, kk * 32 + g * 8, 64);
        f16x8 a1 = afrag(h0b, 16 + rr, kk * 32 + g * 8, 64);
#pragma unroll
        for (int nf = 0; nf < 4; ++nf) {
          f16x8 b = W1[(kk * 32 + nf0 + nf) * 64 + lane];
          acc[0][nf] = MFMA16(a0, b, acc[0][nf]);
          acc[1][nf] = MFMA16(a1, b, acc[1][nf]);
        }
      }
#pragma unroll
      for (int nf = 0; nf < 4; ++nf) {
        const int n = (nf0 + nf) * 16 + rr;
        const float bv = eb1[n];
#pragma unroll
        for (int i = 0; i < 4; ++i) {
          float v0 = fmaxf(acc[0][nf][i] + bv, 0.f);
          float v1 = fmaxf(acc[1][nf][i] + bv, 0.f);
          h1b[hidx(g * 4 + i, n, 64)] = (_Float16)v0;
          h1b[hidx(16 + g * 4 + i, n, 64)] = (_Float16)v1;
        }
      }
    }
    __syncthreads();

    // L2: h2 = relu(h1 @ eW2 + eb2), h1b(nu64) -> slotA(nu16)
    mlayer<16, 64, 16, true>(h1b, slotA, W2, eb2, 8, w, lane, g, rr);
    __syncthreads();

    // h1 now dead: convert session A into h1b (rows 0..15), issue session B loads
    if (pf) {
      CONVA(h1b);
      LOADB(xn);  // in flight across L3+L4
    }

    // L3: h3 = h2 @ eW3 + eb3 (FWHT folded), slotA(nu16) -> slotB(nu8)
    mlayer<4, 16, 8, false>(slotA, slotB, W3, eb3, 4, w, lane, g, rr);
    __syncthreads();
    // L4: h4 = relu(h3 @ dW1' + db1'), slotB(nu8) -> slotA(nu16)
    mlayer<2, 8, 16, true>(slotB, slotA, W4, db1p, 8, w, lane, g, rr);
    __syncthreads();

    if (pf) CONVB(h1b);  // rows 16..31

    // L5: h5 = h4 @ dW2 + db2, slotA(nu16) -> slotC(nu4)
    mlayer<4, 16, 4, false>(slotA, slotC, W5, db2, 2, w, lane, g, rr);
    __syncthreads();

    // ---- L6: out = h5 @ pW' + pb' (waves 0-1) ----
    if (w < 2) {
      f32x4 acc0 = {0.f, 0.f, 0.f, 0.f};
      f32x4 acc1 = {0.f, 0.f, 0.f, 0.f};
      f16x8 a0 = afrag(slotC, rr, g * 8, 4);
      f16x8 a1 = afrag(slotC, 16 + rr, g * 8, 4);
      f16x8 b = W6[w * 64 + lane];
      acc0 = MFMA16(a0, b, acc0);
      acc1 = MFMA16(a1, b, acc1);
      const int n = w * 16 + rr;
      const float bv = pbp[n];
      const size_t rbase = (size_t)(wg + GRID * it) * 32;
#pragma unroll
      for (int i = 0; i < 4; ++i) {
        out[(rbase + g * 4 + i) * 32 + n] = acc0[i] + bv;
        out[(rbase + 16 + g * 4 + i) * 32 + n] = acc1[i] + bv;
      }
    }
    __syncthreads();  // h0-next (in old h1b) complete; slotC safe to reuse
  }
}

extern "C" void kernel_launch(void* const* d_in, const int* in_sizes, int n_in,
                              void* d_out, int out_size, void* d_ws, size_t ws_size,
                              hipStream_t stream) {
  const float* x = (const float*)d_in[0];
  const float* dw1 = (const float*)d_in[1];
  const float* dw2 = (const float*)d_in[2];
  const float* eW1 = (const float*)d_in[3];
  const float* eb1 = (const float*)d_in[4];
  const float* eW2 = (const float*)d_in[5];
  const float* eb2 = (const float*)d_in[6];
  const float* eW3 = (const float*)d_in[7];
  const float* eb3 = (const float*)d_in[8];
  const float* w1c = (const float*)d_in[9];
  const float* w1b = (const float*)d_in[10];
  const float* dW1 = (const float*)d_in[11];
  const float* db1 = (const float*)d_in[12];
  const float* dW2 = (const float*)d_in[13];
  const float* db2 = (const float*)d_in[14];
  const float* w2c = (const float*)d_in[15];
  const float* w2b = (const float*)d_in[16];
  const float* pW = (const float*)d_in[17];
  const float* pb = (const float*)d_in[18];
  char* ws = (char*)d_ws;
  float* out = (float*)d_out;

  prep_kernel<<<dim3(1365), dim3(256), 0, stream>>>(eW1, eW2, eW3, dW1, dW2, pW, w1c, w1b,
                                                    w2c, w2b, db1, pb, ws);
  fused_kernel<<<dim3(GRID), dim3(512), 0, stream>>>(x, dw1, dw2, eb1, eb2, eb3, db2, ws,
                                                     out);
}

// Round 5
// 468.719 us; speedup vs baseline: 1.3692x; 1.3576x over previous
//
#include <hip/hip_runtime.h>

typedef _Float16 f16x8 __attribute__((ext_vector_type(8)));
typedef float f32x4 __attribute__((ext_vector_type(4)));

#define MFMA16(a, b, c) __builtin_amdgcn_mfma_f32_16x16x32_f16(a, b, c, 0, 0, 0)

// ---- ws byte offsets (all 16B aligned) ----
#define OFF_W1   0u        // eW1  512x512 f16 packed (524288 B)
#define OFF_W2   524288u   // eW2  512x128 (131072 B)
#define OFF_W3   655360u   // eW3  128x64  (16384 B)
#define OFF_W4   671744u   // dW1' 64x128  (16384 B)  = (H64 dW1) * w1c/8
#define OFF_W5   688128u   // dW2  128x32  (8192 B)
#define OFF_W6   696320u   // pW'  32x32   (2048 B)   = (H32 pW) * w2c/sqrt(32)
#define OFF_DB1  698368u   // db1' 128 f32 (512 B)    = db1 + w1b*colsum(dW1)
#define OFF_PB   698880u   // pb'  32 f32  (128 B)    = pb  + w2b*colsum(pW)

__device__ inline void packw(int local, int N, const float* __restrict__ W,
                             _Float16* __restrict__ dst) {
  int j = local & 7;
  int lane = (local >> 3) & 63;
  int fi = local >> 9;
  int NF = N >> 4;
  int nf = fi % NF;
  int kk = fi / NF;
  int k = kk * 32 + ((lane >> 4) << 3) + j;
  int n = (nf << 4) + (lane & 15);
  dst[local] = (_Float16)W[k * N + n];
}

__device__ inline void packh(int local, int N, int K, const float* __restrict__ W,
                             _Float16* __restrict__ dst, float scale) {
  int j = local & 7;
  int lane = (local >> 3) & 63;
  int fi = local >> 9;
  int NF = N >> 4;
  int nf = fi % NF;
  int kk = fi / NF;
  int k = kk * 32 + ((lane >> 4) << 3) + j;
  int n = (nf << 4) + (lane & 15);
  float s = 0.f;
  for (int m = 0; m < K; ++m) {
    float v = W[m * N + n];
    s += (__popc(k & m) & 1) ? -v : v;
  }
  dst[local] = (_Float16)(s * scale);
}

extern "C" __global__ __launch_bounds__(256) void prep_kernel(
    const float* __restrict__ eW1, const float* __restrict__ eW2,
    const float* __restrict__ eW3, const float* __restrict__ dW1,
    const float* __restrict__ dW2, const float* __restrict__ pW,
    const float* __restrict__ w1c, const float* __restrict__ w1b,
    const float* __restrict__ w2c, const float* __restrict__ w2b,
    const float* __restrict__ db1, const float* __restrict__ pb,
    char* __restrict__ ws) {
  int idx = blockIdx.x * 256 + threadIdx.x;
  if (idx < 262144) {
    packw(idx, 512, eW1, (_Float16*)(ws + OFF_W1));
  } else if (idx < 327680) {
    packw(idx - 262144, 128, eW2, (_Float16*)(ws + OFF_W2));
  } else if (idx < 335872) {
    packw(idx - 327680, 64, eW3, (_Float16*)(ws + OFF_W3));
  } else if (idx < 344064) {
    packh(idx - 335872, 128, 64, dW1, (_Float16*)(ws + OFF_W4), w1c[0] * 0.125f);
  } else if (idx < 348160) {
    packw(idx - 344064, 32, dW2, (_Float16*)(ws + OFF_W5));
  } else if (idx < 349184) {
    packh(idx - 348160, 32, 32, pW, (_Float16*)(ws + OFF_W6),
          w2c[0] * 0.17677669529663687f);  // 1/sqrt(32)
  } else if (idx < 349312) {
    int n = idx - 349184;
    float s = 0.f;
    for (int m = 0; m < 64; ++m) s += dW1[m * 128 + n];
    ((float*)(ws + OFF_DB1))[n] = db1[n] + w1b[0] * s;
  } else if (idx < 349344) {
    int n = idx - 349312;
    float s = 0.f;
    for (int m = 0; m < 32; ++m) s += pW[m * 32 + n];
    ((float*)(ws + OFF_PB))[n] = pb[n] + w2b[0] * s;
  }
}

// ---- LDS layout: XOR-swizzled row-major; nu = 16B units per row ----
__device__ inline int hidx(int row, int col, int nu) {
  int u = (col >> 3) ^ ((row & 7) & (nu - 1));
  return row * (nu << 3) + (u << 3) + (col & 7);
}

__device__ inline f16x8 afrag(const _Float16* h, int row, int col, int nu) {
  return *(const f16x8*)(h + hidx(row, col, nu));  // col % 8 == 0 -> 16B aligned
}

// Generic layer: out[32][16*NF] = act(in[32][KSTEPS*32] @ W + bias); wave w owns nf=w.
template <int KSTEPS, int NUIN, int NUOUT, bool RELU>
__device__ inline void mlayer(const _Float16* hin, _Float16* hout,
                              const f16x8* __restrict__ Wp, const float* __restrict__ bias,
                              int NF, int w, int lane, int g, int rr) {
  if (w < NF) {
    const int nf = w;
    f32x4 acc0 = {0.f, 0.f, 0.f, 0.f};
    f32x4 acc1 = {0.f, 0.f, 0.f, 0.f};
#pragma unroll
    for (int kk = 0; kk < KSTEPS; ++kk) {
      f16x8 a0 = afrag(hin, rr, kk * 32 + g * 8, NUIN);
      f16x8 a1 = afrag(hin, 16 + rr, kk * 32 + g * 8, NUIN);
      f16x8 b = Wp[(kk * NF + nf) * 64 + lane];
      acc0 = MFMA16(a0, b, acc0);
      acc1 = MFMA16(a1, b, acc1);
    }
    const int n = nf * 16 + rr;
    const float bv = bias[n];
#pragma unroll
    for (int i = 0; i < 4; ++i) {
      float v0 = acc0[i] + bv;
      float v1 = acc1[i] + bv;
      if (RELU) {
        v0 = fmaxf(v0, 0.f);
        v1 = fmaxf(v1, 0.f);
      }
      hout[hidx(g * 4 + i, n, NUOUT)] = (_Float16)v0;
      hout[hidx(16 + g * 4 + i, n, NUOUT)] = (_Float16)v1;
    }
  }
}

// Convert one named float4 (index I in 0..15) -> h0 rows f>>8, cols f&255 / +256
#define CONV1(V, I, H)                                                  \
  do {                                                                  \
    int f_ = tid + (I) * 512;                                           \
    int r_ = f_ >> 8;                                                   \
    int t_ = f_ & 255;                                                  \
    float R_ = (V).x * d10 + (V).y * d11 + (V).z * d12 + (V).w * d13;   \
    float Z_ = (V).x * d20 + (V).y * d21 + (V).z * d22 + (V).w * d23;   \
    (H)[hidx(r_, t_, 64)] = (_Float16)R_;                               \
    (H)[hidx(r_, 256 + t_, 64)] = (_Float16)Z_;                         \
  } while (0)

#define LOADA(P)            \
  do {                      \
    x0 = (P)[tid + 0 * 512]; \
    x1 = (P)[tid + 1 * 512]; \
    x2 = (P)[tid + 2 * 512]; \
    x3 = (P)[tid + 3 * 512]; \
    x4 = (P)[tid + 4 * 512]; \
    x5 = (P)[tid + 5 * 512]; \
    x6 = (P)[tid + 6 * 512]; \
    x7 = (P)[tid + 7 * 512]; \
  } while (0)

#define LOADB(P)             \
  do {                       \
    y0 = (P)[tid + 8 * 512];  \
    y1 = (P)[tid + 9 * 512];  \
    y2 = (P)[tid + 10 * 512]; \
    y3 = (P)[tid + 11 * 512]; \
    y4 = (P)[tid + 12 * 512]; \
    y5 = (P)[tid + 13 * 512]; \
    y6 = (P)[tid + 14 * 512]; \
    y7 = (P)[tid + 15 * 512]; \
  } while (0)

#define CONVA(H)        \
  do {                  \
    CONV1(x0, 0, H);    \
    CONV1(x1, 1, H);    \
    CONV1(x2, 2, H);    \
    CONV1(x3, 3, H);    \
    CONV1(x4, 4, H);    \
    CONV1(x5, 5, H);    \
    CONV1(x6, 6, H);    \
    CONV1(x7, 7, H);    \
  } while (0)

#define CONVB(H)        \
  do {                  \
    CONV1(y0, 8, H);    \
    CONV1(y1, 9, H);    \
    CONV1(y2, 10, H);   \
    CONV1(y3, 11, H);   \
    CONV1(y4, 12, H);   \
    CONV1(y5, 13, H);   \
    CONV1(y6, 14, H);   \
    CONV1(y7, 15, H);   \
  } while (0)

// ---- persistent fused kernel: 512 WGs x 4 blocks of 32 rows ----
// LDS (80 KB total -> 2 WG/CU):
//   hA/hB (32K each): h0 / h1, roles swap by iteration parity.
//     h1's buffer is fully dead after L2 -> next-block h0 converted into it.
//   side (16K): slotA = h2/h4 (nu16, 8K), slotB = h3 (nu8, 4K), slotC = h5 (nu4, 2K)
// __launch_bounds__ 2nd arg = 2 (NOT 4): 4 forced 32 waves/CU -> 64-VGPR cap ->
// staging regs spilled to scratch (R1-R3: 530 MB WRITE_SIZE). 2 blocks/CU is the
// LDS-bound occupancy anyway and lifts the cap to 128 VGPRs.
#define NB 4
#define GRID 512

extern "C" __global__ __launch_bounds__(512, 2) void fused_kernel(
    const float* __restrict__ x, const float* __restrict__ dw1,
    const float* __restrict__ dw2, const float* __restrict__ eb1,
    const float* __restrict__ eb2, const float* __restrict__ eb3,
    const float* __restrict__ db2, const char* __restrict__ ws,
    float* __restrict__ out) {
  __shared__ __align__(16) _Float16 hA[32 * 512];
  __shared__ __align__(16) _Float16 hB[32 * 512];
  __shared__ __align__(16) _Float16 side[8192];
  _Float16* const slotA = side;         // 32x128 nu16
  _Float16* const slotB = side + 4096;  // 32x64  nu8
  _Float16* const slotC = side + 6144;  // 32x32  nu4

  const int tid = threadIdx.x;
  const int wg = blockIdx.x;
  const int lane = tid & 63;
  const int w = tid >> 6;
  const int g = lane >> 4;
  const int rr = lane & 15;

  const float d10 = dw1[0], d11 = dw1[1], d12 = dw1[2], d13 = dw1[3];
  const float d20 = dw2[0], d21 = dw2[1], d22 = dw2[2], d23 = dw2[3];

  const f16x8* __restrict__ W1 = (const f16x8*)(ws + OFF_W1);
  const f16x8* __restrict__ W2 = (const f16x8*)(ws + OFF_W2);
  const f16x8* __restrict__ W3 = (const f16x8*)(ws + OFF_W3);
  const f16x8* __restrict__ W4 = (const f16x8*)(ws + OFF_W4);
  const f16x8* __restrict__ W5 = (const f16x8*)(ws + OFF_W5);
  const f16x8* __restrict__ W6 = (const f16x8*)(ws + OFF_W6);
  const float* __restrict__ db1p = (const float*)(ws + OFF_DB1);
  const float* __restrict__ pbp = (const float*)(ws + OFF_PB);

  float4 x0, x1, x2, x3, x4, x5, x6, x7;
  float4 y0, y1, y2, y3, y4, y5, y6, y7;

  // ---- prologue: stage + convert block wg into hA ----
  {
    const float4* __restrict__ xp = (const float4*)x + (size_t)wg * 8192;
    LOADA(xp);
    LOADB(xp);
    CONVA(hA);
    CONVB(hA);
  }
  __syncthreads();

  for (int it = 0; it < NB; ++it) {
    const bool pf = (it < NB - 1);
    _Float16* const h0b = (it & 1) ? hB : hA;
    _Float16* const h1b = (it & 1) ? hA : hB;
    const float4* __restrict__ xn =
        (const float4*)x + (size_t)(wg + GRID * (it + 1)) * 8192;

    if (pf) LOADA(xn);  // in flight across L1+L2

    // ---- L1: h1 = relu(h0 @ eW1 + eb1), h0b -> h1b; 8 waves x 4 nf ----
    {
      f32x4 acc[2][4];
#pragma unroll
      for (int m = 0; m < 2; ++m)
#pragma unroll
        for (int n = 0; n < 4; ++n) acc[m][n] = (f32x4){0.f, 0.f, 0.f, 0.f};
      const int nf0 = w * 4;
#pragma unroll
      for (int kk = 0; kk < 16; ++kk) {
        f16x8 a0 = afrag(h0b, rr, kk * 32 + g * 8, 64);
        f16x8 a1 = afrag(h0b, 16 + rr, kk * 32 + g * 8, 64);
#pragma unroll
        for (int nf = 0; nf < 4; ++nf) {
          f16x8 b = W1[(kk * 32 + nf0 + nf) * 64 + lane];
          acc[0][nf] = MFMA16(a0, b, acc[0][nf]);
          acc[1][nf] = MFMA16(a1, b, acc[1][nf]);
        }
      }
#pragma unroll
      for (int nf = 0; nf < 4; ++nf) {
        const int n = (nf0 + nf) * 16 + rr;
        const float bv = eb1[n];
#pragma unroll
        for (int i = 0; i < 4; ++i) {
          float v0 = fmaxf(acc[0][nf][i] + bv, 0.f);
          float v1 = fmaxf(acc[1][nf][i] + bv, 0.f);
          h1b[hidx(g * 4 + i, n, 64)] = (_Float16)v0;
          h1b[hidx(16 + g * 4 + i, n, 64)] = (_Float16)v1;
        }
      }
    }
    __syncthreads();

    // L2: h2 = relu(h1 @ eW2 + eb2), h1b(nu64) -> slotA(nu16)
    mlayer<16, 64, 16, true>(h1b, slotA, W2, eb2, 8, w, lane, g, rr);
    __syncthreads();

    // h1 now dead: convert session A into h1b, issue session B loads
    if (pf) {
      CONVA(h1b);
      LOADB(xn);  // in flight across L3+L4
    }

    // L3: h3 = h2 @ eW3 + eb3 (FWHT folded), slotA(nu16) -> slotB(nu8)
    mlayer<4, 16, 8, false>(slotA, slotB, W3, eb3, 4, w, lane, g, rr);
    __syncthreads();
    // L4: h4 = relu(h3 @ dW1' + db1'), slotB(nu8) -> slotA(nu16)
    mlayer<2, 8, 16, true>(slotB, slotA, W4, db1p, 8, w, lane, g, rr);
    __syncthreads();

    if (pf) CONVB(h1b);

    // L5: h5 = h4 @ dW2 + db2, slotA(nu16) -> slotC(nu4)
    mlayer<4, 16, 4, false>(slotA, slotC, W5, db2, 2, w, lane, g, rr);
    __syncthreads();

    // ---- L6: out = h5 @ pW' + pb' (waves 0-1) ----
    if (w < 2) {
      f32x4 acc0 = {0.f, 0.f, 0.f, 0.f};
      f32x4 acc1 = {0.f, 0.f, 0.f, 0.f};
      f16x8 a0 = afrag(slotC, rr, g * 8, 4);
      f16x8 a1 = afrag(slotC, 16 + rr, g * 8, 4);
      f16x8 b = W6[w * 64 + lane];
      acc0 = MFMA16(a0, b, acc0);
      acc1 = MFMA16(a1, b, acc1);
      const int n = w * 16 + rr;
      const float bv = pbp[n];
      const size_t rbase = (size_t)(wg + GRID * it) * 32;
#pragma unroll
      for (int i = 0; i < 4; ++i) {
        out[(rbase + g * 4 + i) * 32 + n] = acc0[i] + bv;
        out[(rbase + 16 + g * 4 + i) * 32 + n] = acc1[i] + bv;
      }
    }
    __syncthreads();  // h0-next (in old h1b) complete; slotC safe to reuse
  }
}

extern "C" void kernel_launch(void* const* d_in, const int* in_sizes, int n_in,
                              void* d_out, int out_size, void* d_ws, size_t ws_size,
                              hipStream_t stream) {
  const float* x = (const float*)d_in[0];
  const float* dw1 = (const float*)d_in[1];
  const float* dw2 = (const float*)d_in[2];
  const float* eW1 = (const float*)d_in[3];
  const float* eb1 = (const float*)d_in[4];
  const float* eW2 = (const float*)d_in[5];
  const float* eb2 = (const float*)d_in[6];
  const float* eW3 = (const float*)d_in[7];
  const float* eb3 = (const float*)d_in[8];
  const float* w1c = (const float*)d_in[9];
  const float* w1b = (const float*)d_in[10];
  const float* dW1 = (const float*)d_in[11];
  const float* db1 = (const float*)d_in[12];
  const float* dW2 = (const float*)d_in[13];
  const float* db2 = (const float*)d_in[14];
  const float* w2c = (const float*)d_in[15];
  const float* w2b = (const float*)d_in[16];
  const float* pW = (const float*)d_in[17];
  const float* pb = (const float*)d_in[18];
  char* ws = (char*)d_ws;
  float* out = (float*)d_out;

  prep_kernel<<<dim3(1365), dim3(256), 0, stream>>>(eW1, eW2, eW3, dW1, dW2, pW, w1c, w1b,
                                                    w2c, w2b, db1, pb, ws);
  fused_kernel<<<dim3(GRID), dim3(512), 0, stream>>>(x, dw1, dw2, eb1, eb2, eb3, db2, ws,
                                                     out);
}

// Round 6
// 104.176 us; speedup vs baseline: 6.1605x; 4.4993x over previous
//
#include <hip/hip_runtime.h>

typedef _Float16 f16x8 __attribute__((ext_vector_type(8)));
typedef float f32x4 __attribute__((ext_vector_type(4)));

#define MFMA16(a, b, c) __builtin_amdgcn_mfma_f32_16x16x32_f16(a, b, c, 0, 0, 0)

// ---- ws byte offsets (all 16B aligned) ----
#define OFF_W1   0u        // eW1  512x512 f16 packed (524288 B)
#define OFF_W2   524288u   // eW2  512x128 (131072 B)
#define OFF_W3   655360u   // eW3  128x64  (16384 B)
#define OFF_W4   671744u   // dW1' 64x128  (16384 B)  = (H64 dW1) * w1c/8
#define OFF_W5   688128u   // dW2  128x32  (8192 B)
#define OFF_W6   696320u   // pW'  32x32   (2048 B)   = (H32 pW) * w2c/sqrt(32)
#define OFF_DB1  698368u   // db1' 128 f32 (512 B)    = db1 + w1b*colsum(dW1)
#define OFF_PB   698880u   // pb'  32 f32  (128 B)    = pb  + w2b*colsum(pW)

__device__ inline void packw(int local, int N, const float* __restrict__ W,
                             _Float16* __restrict__ dst) {
  int j = local & 7;
  int lane = (local >> 3) & 63;
  int fi = local >> 9;
  int NF = N >> 4;
  int nf = fi % NF;
  int kk = fi / NF;
  int k = kk * 32 + ((lane >> 4) << 3) + j;
  int n = (nf << 4) + (lane & 15);
  dst[local] = (_Float16)W[k * N + n];
}

__device__ inline void packh(int local, int N, int K, const float* __restrict__ W,
                             _Float16* __restrict__ dst, float scale) {
  int j = local & 7;
  int lane = (local >> 3) & 63;
  int fi = local >> 9;
  int NF = N >> 4;
  int nf = fi % NF;
  int kk = fi / NF;
  int k = kk * 32 + ((lane >> 4) << 3) + j;
  int n = (nf << 4) + (lane & 15);
  float s = 0.f;
  for (int m = 0; m < K; ++m) {
    float v = W[m * N + n];
    s += (__popc(k & m) & 1) ? -v : v;
  }
  dst[local] = (_Float16)(s * scale);
}

extern "C" __global__ __launch_bounds__(256) void prep_kernel(
    const float* __restrict__ eW1, const float* __restrict__ eW2,
    const float* __restrict__ eW3, const float* __restrict__ dW1,
    const float* __restrict__ dW2, const float* __restrict__ pW,
    const float* __restrict__ w1c, const float* __restrict__ w1b,
    const float* __restrict__ w2c, const float* __restrict__ w2b,
    const float* __restrict__ db1, const float* __restrict__ pb,
    char* __restrict__ ws) {
  int idx = blockIdx.x * 256 + threadIdx.x;
  if (idx < 262144) {
    packw(idx, 512, eW1, (_Float16*)(ws + OFF_W1));
  } else if (idx < 327680) {
    packw(idx - 262144, 128, eW2, (_Float16*)(ws + OFF_W2));
  } else if (idx < 335872) {
    packw(idx - 327680, 64, eW3, (_Float16*)(ws + OFF_W3));
  } else if (idx < 344064) {
    packh(idx - 335872, 128, 64, dW1, (_Float16*)(ws + OFF_W4), w1c[0] * 0.125f);
  } else if (idx < 348160) {
    packw(idx - 344064, 32, dW2, (_Float16*)(ws + OFF_W5));
  } else if (idx < 349184) {
    packh(idx - 348160, 32, 32, pW, (_Float16*)(ws + OFF_W6),
          w2c[0] * 0.17677669529663687f);  // 1/sqrt(32)
  } else if (idx < 349312) {
    int n = idx - 349184;
    float s = 0.f;
    for (int m = 0; m < 64; ++m) s += dW1[m * 128 + n];
    ((float*)(ws + OFF_DB1))[n] = db1[n] + w1b[0] * s;
  } else if (idx < 349344) {
    int n = idx - 349312;
    float s = 0.f;
    for (int m = 0; m < 32; ++m) s += pW[m * 32 + n];
    ((float*)(ws + OFF_PB))[n] = pb[n] + w2b[0] * s;
  }
}

// ---- LDS layout: XOR-swizzled row-major; nu = 16B units per row ----
__device__ inline int hidx(int row, int col, int nu) {
  int u = (col >> 3) ^ ((row & 7) & (nu - 1));
  return row * (nu << 3) + (u << 3) + (col & 7);
}

__device__ inline f16x8 afrag(const _Float16* h, int row, int col, int nu) {
  return *(const f16x8*)(h + hidx(row, col, nu));  // col % 8 == 0 -> 16B aligned
}

// Generic epilogue layer: out[64][16*NFtot] slice; wave computes MT m-tiles at
// column-tile nf0. Each B fragment loaded once per wave. All acc statically indexed.
template <int KK, int NUIN, int NUOUT, bool RELU, int MT>
__device__ inline void layerN(const _Float16* hin, _Float16* hout,
                              const f16x8* __restrict__ Wp,
                              const float* __restrict__ bias, int NFtot, int m0,
                              int nf0, int lane, int g, int rr) {
  f32x4 acc[MT];
#pragma unroll
  for (int m = 0; m < MT; ++m) acc[m] = (f32x4){0.f, 0.f, 0.f, 0.f};
#pragma unroll
  for (int kk = 0; kk < KK; ++kk) {
    f16x8 b = Wp[(kk * NFtot + nf0) * 64 + lane];
#pragma unroll
    for (int m = 0; m < MT; ++m) {
      f16x8 a = afrag(hin, (m0 + m) * 16 + rr, kk * 32 + g * 8, NUIN);
      acc[m] = MFMA16(a, b, acc[m]);
    }
  }
  const int n = nf0 * 16 + rr;
  const float bv = bias[n];
#pragma unroll
  for (int m = 0; m < MT; ++m) {
#pragma unroll
    for (int i = 0; i < 4; ++i) {
      float v = acc[m][i] + bv;
      if (RELU) v = fmaxf(v, 0.f);
      hout[hidx((m0 + m) * 16 + g * 4 + i, n, NUOUT)] = (_Float16)v;
    }
  }
}

// Convert one float4 (x cols 4q..4q+3, q = e + 8K) into slice col q of SB par.
// Slice layout: 64 rows x 32 cols f16, nu4 swizzle; R at +0, Z at +2048.
#define CONV1C(V, K, PAR)                                               \
  do {                                                                  \
    int ix_ = r * 32 + (((K) ^ (r & 3)) << 3) + e;                      \
    float R_ = (V).x * d10 + (V).y * d11 + (V).z * d12 + (V).w * d13;   \
    float Z_ = (V).x * d20 + (V).y * d21 + (V).z * d22 + (V).w * d23;   \
    SB[(PAR) * 4096 + ix_] = (_Float16)R_;                              \
    SB[(PAR) * 4096 + 2048 + ix_] = (_Float16)Z_;                       \
  } while (0)

// ---- fused kernel: grid 1024, one 64-row block per WG, 512 threads ----
// LDS (80 KB -> 2 WG/CU, 16 waves/CU, VGPR cap 128):
//   H1 (64 KB): h1 [64x512 nu64] during L1/L2; after L2: h3 [64x64 nu8]@0,
//               h4 [64x128 nu16]@4096, h5 [64x32 nu4]@12288 (elem offsets)
//   SB (16 KB): L1 x-slice double buffer sb[par][R/Z][64x32 nu4]; after L1: h2 [64x128 nu16]
// x is streamed INSIDE L1: chunk c (x cols 128c..128c+127) -> K-slices kk=c (R)
// and kk=8+c (Z); 4 float4/thread live only within one c-iteration (no
// cross-layer staging -> no spill; WRITE_SIZE is the regression check).
#define GRID 1024

extern "C" __global__ __launch_bounds__(512, 2) void fused_kernel(
    const float* __restrict__ x, const float* __restrict__ dw1,
    const float* __restrict__ dw2, const float* __restrict__ eb1,
    const float* __restrict__ eb2, const float* __restrict__ eb3,
    const float* __restrict__ db2, const char* __restrict__ ws,
    float* __restrict__ out) {
  __shared__ __align__(16) _Float16 H1[32768];
  __shared__ __align__(16) _Float16 SB[8192];

  const int tid = threadIdx.x;
  const int wg = blockIdx.x;
  const int lane = tid & 63;
  const int w = tid >> 6;
  const int g = lane >> 4;
  const int rr = lane & 15;
  const int r = tid >> 3;  // x-staging row 0..63
  const int e = tid & 7;   // x-staging sub-col

  const float d10 = dw1[0], d11 = dw1[1], d12 = dw1[2], d13 = dw1[3];
  const float d20 = dw2[0], d21 = dw2[1], d22 = dw2[2], d23 = dw2[3];

  const f16x8* __restrict__ W1 = (const f16x8*)(ws + OFF_W1);
  const f16x8* __restrict__ W2 = (const f16x8*)(ws + OFF_W2);
  const f16x8* __restrict__ W3 = (const f16x8*)(ws + OFF_W3);
  const f16x8* __restrict__ W4 = (const f16x8*)(ws + OFF_W4);
  const f16x8* __restrict__ W5 = (const f16x8*)(ws + OFF_W5);
  const f16x8* __restrict__ W6 = (const f16x8*)(ws + OFF_W6);
  const float* __restrict__ db1p = (const float*)(ws + OFF_DB1);
  const float* __restrict__ pbp = (const float*)(ws + OFF_PB);

  // per-thread x row pointer (float4 granularity; 256 float4 per row)
  const float4* __restrict__ xp = (const float4*)x + ((size_t)wg * 64 + r) * 256;

  float4 v0, v1, v2, v3;

  // ---- L1 prologue: chunk 0 -> SB par 0 ----
  v0 = xp[e];
  v1 = xp[e + 8];
  v2 = xp[e + 16];
  v3 = xp[e + 24];
  CONV1C(v0, 0, 0);
  CONV1C(v1, 1, 0);
  CONV1C(v2, 2, 0);
  CONV1C(v3, 3, 0);
  __syncthreads();

  // ---- L1: h1 = relu(h0 @ eW1 + eb1); acc 4m x 4nf per wave ----
  f32x4 acc[4][4];
#pragma unroll
  for (int m = 0; m < 4; ++m)
#pragma unroll
    for (int n = 0; n < 4; ++n) acc[m][n] = (f32x4){0.f, 0.f, 0.f, 0.f};

  for (int c = 0; c < 8; ++c) {
    const int par = c & 1;
    if (c < 7) {  // issue next chunk; consumed at iteration end only
      const int cb = (c + 1) * 32;
      v0 = xp[cb + e];
      v1 = xp[cb + e + 8];
      v2 = xp[cb + e + 16];
      v3 = xp[cb + e + 24];
    }
#pragma unroll
    for (int S = 0; S < 2; ++S) {  // R slice kk=c, Z slice kk=8+c
      const _Float16* sl = SB + par * 4096 + S * 2048;
      const int kk = S ? (8 + c) : c;
      f16x8 a0 = afrag(sl, rr, g * 8, 4);
      f16x8 a1 = afrag(sl, 16 + rr, g * 8, 4);
      f16x8 a2 = afrag(sl, 32 + rr, g * 8, 4);
      f16x8 a3 = afrag(sl, 48 + rr, g * 8, 4);
#pragma unroll
      for (int nf = 0; nf < 4; ++nf) {
        f16x8 b = W1[(kk * 32 + w * 4 + nf) * 64 + lane];
        acc[0][nf] = MFMA16(a0, b, acc[0][nf]);
        acc[1][nf] = MFMA16(a1, b, acc[1][nf]);
        acc[2][nf] = MFMA16(a2, b, acc[2][nf]);
        acc[3][nf] = MFMA16(a3, b, acc[3][nf]);
      }
    }
    if (c < 7) {
      const int np = par ^ 1;
      CONV1C(v0, 0, np);
      CONV1C(v1, 1, np);
      CONV1C(v2, 2, np);
      CONV1C(v3, 3, np);
    }
    __syncthreads();
  }

  // h1 store: wave w owns cols [w*64, w*64+64), all 64 rows
#pragma unroll
  for (int mt = 0; mt < 4; ++mt) {
#pragma unroll
    for (int nf = 0; nf < 4; ++nf) {
      const int n = (w * 4 + nf) * 16 + rr;
      const float bv = eb1[n];
#pragma unroll
      for (int i = 0; i < 4; ++i) {
        float v = fmaxf(acc[mt][nf][i] + bv, 0.f);
        H1[hidx(mt * 16 + g * 4 + i, n, 64)] = (_Float16)v;
      }
    }
  }
  __syncthreads();

  // L2: h2 = relu(h1 @ eW2 + eb2)  [64x512]@[512x128] -> SB (h2, nu16)
  layerN<16, 64, 16, true, 4>(H1, SB, W2, eb2, 8, 0, w, lane, g, rr);
  __syncthreads();
  // L3: h3 = h2 @ eW3 + eb3 (FWHT folded fwd)  -> H1@0 (nu8)
  layerN<4, 16, 8, false, 2>(SB, H1, W3, eb3, 4, (w >> 2) * 2, w & 3, lane, g, rr);
  __syncthreads();
  // L4: h4 = relu(h3 @ dW1' + db1')  -> H1@4096 (nu16)
  layerN<2, 8, 16, true, 4>(H1, H1 + 4096, W4, db1p, 8, 0, w, lane, g, rr);
  __syncthreads();
  // L5: h5 = h4 @ dW2 + db2  -> H1@12288 (nu4)
  layerN<4, 16, 4, false, 1>(H1 + 4096, H1 + 12288, W5, db2, 2, w >> 1, w & 1,
                             lane, g, rr);
  __syncthreads();

  // L6: out = h5 @ pW' + pb'; one tile per wave
  {
    const _Float16* h5 = H1 + 12288;
    const int m0 = w >> 1;
    const int nf0 = w & 1;
    f16x8 a = afrag(h5, m0 * 16 + rr, g * 8, 4);
    f16x8 b = W6[nf0 * 64 + lane];
    f32x4 o = MFMA16(a, b, ((f32x4){0.f, 0.f, 0.f, 0.f}));
    const int n = nf0 * 16 + rr;
    const float bv = pbp[n];
    const size_t rbase = (size_t)wg * 64 + m0 * 16;
#pragma unroll
    for (int i = 0; i < 4; ++i) {
      out[(rbase + g * 4 + i) * 32 + n] = o[i] + bv;
    }
  }
}

extern "C" void kernel_launch(void* const* d_in, const int* in_sizes, int n_in,
                              void* d_out, int out_size, void* d_ws, size_t ws_size,
                              hipStream_t stream) {
  const float* x = (const float*)d_in[0];
  const float* dw1 = (const float*)d_in[1];
  const float* dw2 = (const float*)d_in[2];
  const float* eW1 = (const float*)d_in[3];
  const float* eb1 = (const float*)d_in[4];
  const float* eW2 = (const float*)d_in[5];
  const float* eb2 = (const float*)d_in[6];
  const float* eW3 = (const float*)d_in[7];
  const float* eb3 = (const float*)d_in[8];
  const float* w1c = (const float*)d_in[9];
  const float* w1b = (const float*)d_in[10];
  const float* dW1 = (const float*)d_in[11];
  const float* db1 = (const float*)d_in[12];
  const float* dW2 = (const float*)d_in[13];
  const float* db2 = (const float*)d_in[14];
  const float* w2c = (const float*)d_in[15];
  const float* w2b = (const float*)d_in[16];
  const float* pW = (const float*)d_in[17];
  const float* pb = (const float*)d_in[18];
  char* ws = (char*)d_ws;
  float* out = (float*)d_out;

  prep_kernel<<<dim3(1365), dim3(256), 0, stream>>>(eW1, eW2, eW3, dW1, dW2, pW, w1c, w1b,
                                                    w2c, w2b, db1, pb, ws);
  fused_kernel<<<dim3(GRID), dim3(512), 0, stream>>>(x, dw1, dw2, eb1, eb2, eb3, db2, ws,
                                                     out);
}